// Round 1
// baseline (521.879 us; speedup 1.0000x reference)
//
#include <hip/hip_runtime.h>
#include <cstdint>

#define NUM_CLASSES 81
#define BB 32
#define PP 32768
#define CA 64                               // anchors per chunk
#define TPB 256
#define CHUNK_FLOATS (CA * NUM_CLASSES)     // 5184
#define CHUNK_F4 (CHUNK_FLOATS / 4)         // 1296 = 5*256 + 16
#define NCHUNK (BB * PP / CA)               // 16384
#define GRID_MAIN 768                       // 3 blocks/CU (LDS-limited)
#define NP_STRIDE 32                        // num_pos padded: 1 counter per 128 B

// direct global->LDS, 16 B per lane; LDS dest = wave-uniform base + lane*16
#define GLDS16(g, s)                                              \
    __builtin_amdgcn_global_load_lds(                             \
        (const __attribute__((address_space(1))) void*)(g),       \
        (__attribute__((address_space(3))) void*)(s), 16, 0, 0)

__device__ __forceinline__ unsigned f2key(float f) {
    unsigned u = __float_as_uint(f);
    return u ^ (unsigned)(((int)u >> 31) | (int)0x80000000u);
}
__device__ __forceinline__ float key2f(unsigned k) {
    unsigned u = (k & 0x80000000u) ? (k ^ 0x80000000u) : ~k;
    return __uint_as_float(u);
}

// ---- workspace layout (after the 4 MB loss_c array) ----
// off0+0    : acc[4]  (float)   acc0=loss_l, acc1=pos ce, acc2=neg ce (+tie extra)
// off0+256  : num_pos[32*NP_STRIDE] (int, stride 32 ints = 128 B)
// zero words = 64 + 32*32 = 1088

__global__ void mbl_zero_kernel(unsigned* __restrict__ p, int n) {
    for (int i = threadIdx.x; i < n; i += 256) p[i] = 0u;
}

__global__ __launch_bounds__(TPB, 4) void mbl_main_kernel(
    const float* __restrict__ loc_t, const float* __restrict__ loc_data,
    const int* __restrict__ conf_t, const float* __restrict__ conf,
    float* __restrict__ loss_c, float* __restrict__ acc, int* __restrict__ num_pos)
{
    __shared__ __align__(16) float tile[2][CHUNK_FLOATS];   // 41472 B
    __shared__ float wred[2][TPB / 64];

    const int t = threadIdx.x;
    const int lane = t & 63;
    const int w = t >> 6;
    const int q = lane >> 4;                  // quarter 0..3
    const int a_loc = (w << 4) | (lane & 15); // anchor-in-chunk 0..63

    float sum_ll = 0.f, sum_pce = 0.f;

    int c = blockIdx.x;
    {   // prologue: stage chunk c into buffer 0 (async, drained at first barrier)
        const float* src = conf + (size_t)c * CHUNK_FLOATS;
        #pragma unroll
        for (int i = 0; i < 5; ++i) {
            const int f = t + i * TPB;
            GLDS16(src + f * 4, &tile[0][f * 4]);
        }
        if (t < CHUNK_F4 - 5 * TPB) {
            const int f = t + 5 * TPB;
            GLDS16(src + f * 4, &tile[0][f * 4]);
        }
    }
    int parity = 0;
    const int stride = gridDim.x;
    for (; c < NCHUNK; c += stride) {
        __syncthreads();  // staged buffer[parity] ready (vmcnt drained); prior compute done
        const int nc = c + stride;
        if (nc < NCHUNK) {   // async-stage next chunk into the other buffer
            const float* src = conf + (size_t)nc * CHUNK_FLOATS;
            float* dst = tile[parity ^ 1];
            #pragma unroll
            for (int i = 0; i < 5; ++i) {
                const int f = t + i * TPB;
                GLDS16(src + f * 4, dst + f * 4);
            }
            if (t < CHUNK_F4 - 5 * TPB) {
                const int f = t + 5 * TPB;
                GLDS16(src + f * 4, dst + f * 4);
            }
        }
        // ---- compute chunk c from tile[parity] (loads for nc stay in flight) ----
        const float* cp = tile[parity] + a_loc * NUM_CLASSES + q * 20;
        float s = 0.f;
        #pragma unroll
        for (int j = 0; j < 20; ++j) s += __expf(cp[j]);
        if (q == 3) s += __expf(cp[20]);
        s += __shfl_xor(s, 16);
        s += __shfl_xor(s, 32);              // all 4 quarters combined

        bool posl = false;
        if (q == 0) {
            const int idx = c * CA + a_loc;
            const int label = conf_t[idx];
            posl = label > 0;
            const bool regard = label == -1;
            const int lab = label < 0 ? 0 : label;
            const float g = tile[parity][a_loc * NUM_CLASSES + lab];
            const float ce = __logf(s) - g;
            loss_c[idx] = (posl || regard) ? 0.f : ce;
            if (posl) {
                float4 a4 = ((const float4*)loc_data)[idx];
                float4 b4 = ((const float4*)loc_t)[idx];
                float d0 = fabsf(a4.x - b4.x), d1 = fabsf(a4.y - b4.y);
                float d2 = fabsf(a4.z - b4.z), d3 = fabsf(a4.w - b4.w);
                sum_ll += (d0 < 1.f) ? 0.5f * d0 * d0 : d0 - 0.5f;
                sum_ll += (d1 < 1.f) ? 0.5f * d1 * d1 : d1 - 0.5f;
                sum_ll += (d2 < 1.f) ? 0.5f * d2 * d2 : d2 - 0.5f;
                sum_ll += (d3 < 1.f) ? 0.5f * d3 * d3 : d3 - 0.5f;
                sum_pce += ce;
            }
        }
        unsigned long long bal = __ballot(posl);
        if (lane == 0 && bal)
            atomicAdd(&num_pos[(c >> 9) * NP_STRIDE], (int)__popcll(bal));
        parity ^= 1;
    }
    // reduce scalars
    #pragma unroll
    for (int off = 32; off > 0; off >>= 1) {
        sum_ll += __shfl_down(sum_ll, off);
        sum_pce += __shfl_down(sum_pce, off);
    }
    if (lane == 0) { wred[0][w] = sum_ll; wred[1][w] = sum_pce; }
    __syncthreads();
    if (t == 0) {
        float s0 = 0.f, s1 = 0.f;
        #pragma unroll
        for (int i = 0; i < TPB / 64; ++i) { s0 += wred[0][i]; s1 += wred[1][i]; }
        atomicAdd(&acc[0], s0);
        atomicAdd(&acc[1], s1);
    }
}

// One block per batch row. Whole row (32768 keys) lives in registers (32/thread).
// 4-pass radix select (MSB->LSB) with per-wave private LDS histograms, then the
// top-k sum + tie correction goes straight to acc[2]. Replaces 9 kernels.
__global__ __launch_bounds__(1024, 1) void mbl_select_kernel(
    const float* __restrict__ loss_c, const int* __restrict__ num_pos,
    float* __restrict__ acc)
{
    const int b = blockIdx.x;
    const int t = threadIdx.x;
    const int w = t >> 6;                     // wave 0..15

    __shared__ unsigned hw_[16][256];         // per-wave histograms, 16 KB
    __shared__ unsigned suf[256];
    __shared__ unsigned sh_digit, sh_rem, sh_k;
    __shared__ float wsum[16];

    if (t == 0) {
        int kk = 3 * num_pos[b * NP_STRIDE];
        if (kk > PP - 1) kk = PP - 1;
        sh_k = (kk <= 0) ? 0u : (unsigned)kk;
    }

    // load row -> order-preserving keys in registers
    unsigned key[32];
    const float4* r4 = (const float4*)(loss_c + (size_t)b * PP);
    #pragma unroll
    for (int i = 0; i < 8; ++i) {
        float4 v = r4[t + i * 1024];
        key[4 * i + 0] = f2key(v.x); key[4 * i + 1] = f2key(v.y);
        key[4 * i + 2] = f2key(v.z); key[4 * i + 3] = f2key(v.w);
    }
    __syncthreads();
    unsigned krem = sh_k;
    if (krem == 0u) return;                   // uniform across block

    unsigned pref = 0u;
    #pragma unroll
    for (int p = 0; p < 4; ++p) {
        const int shift = 24 - 8 * p;
        const unsigned mask = (p == 0) ? 0u : (0xFFFFFFFFu << (shift + 8));

        // zero per-wave histograms (4096 words / 1024 threads)
        #pragma unroll
        for (int i = 0; i < 4; ++i) ((unsigned*)hw_)[t + i * 1024] = 0u;
        __syncthreads();
        #pragma unroll
        for (int j = 0; j < 32; ++j)
            if ((key[j] & mask) == pref)
                atomicAdd(&hw_[w][(key[j] >> shift) & 255u], 1u);
        __syncthreads();
        // merge 16 wave-histograms -> suf
        if (t < 256) {
            unsigned s = 0u;
            #pragma unroll
            for (int i = 0; i < 16; ++i) s += hw_[i][t];
            suf[t] = s;
        }
        __syncthreads();
        // suffix scan over 256 bins
        for (int step = 1; step < 256; step <<= 1) {
            unsigned v = 0u;
            if (t < 256) v = suf[t] + ((t + step < 256) ? suf[t + step] : 0u);
            __syncthreads();
            if (t < 256) suf[t] = v;
            __syncthreads();
        }
        // pick digit: unique t with suf[t] >= krem > suf[t+1]
        if (t < 256) {
            unsigned above = (t == 255) ? 0u : suf[t + 1];
            if (suf[t] >= krem && above < krem) {
                sh_digit = (unsigned)t;
                sh_rem = krem - above;
            }
        }
        __syncthreads();
        pref |= sh_digit << shift;
        krem = sh_rem;
    }
    // pref = exact 32-bit threshold key; krem = #elements equal to it to include
    float partial = 0.f;
    #pragma unroll
    for (int j = 0; j < 32; ++j)
        if (key[j] > pref) partial += key2f(key[j]);
    #pragma unroll
    for (int off = 32; off > 0; off >>= 1) partial += __shfl_down(partial, off);
    if ((t & 63) == 0) wsum[w] = partial;
    __syncthreads();
    if (t == 0) {
        float s = 0.f;
        #pragma unroll
        for (int i = 0; i < 16; ++i) s += wsum[i];
        s += (float)krem * key2f(pref);       // tie correction
        atomicAdd(&acc[2], s);
    }
}

__global__ void mbl_final_kernel(const float* __restrict__ acc,
                                 const int* __restrict__ num_pos,
                                 float* __restrict__ out)
{
    if (threadIdx.x == 0 && blockIdx.x == 0) {
        int n = 0;
        for (int i = 0; i < BB; ++i) n += num_pos[i * NP_STRIDE];
        const float N = (float)n;
        out[0] = acc[0] / N;
        out[1] = (acc[1] + acc[2]) / N;
    }
}

extern "C" void kernel_launch(void* const* d_in, const int* in_sizes, int n_in,
                              void* d_out, int out_size, void* d_ws, size_t ws_size,
                              hipStream_t stream) {
    const float* loc_t    = (const float*)d_in[0];
    const float* loc_data = (const float*)d_in[1];
    const int*   conf_t   = (const int*)d_in[2];
    const float* conf     = (const float*)d_in[3];
    float* out = (float*)d_out;

    char* ws = (char*)d_ws;
    const size_t off0 = (size_t)BB * PP * sizeof(float);   // 4 MB loss_c
    float* loss_c  = (float*)ws;
    float* acc     = (float*)(ws + off0);
    int*   num_pos = (int*)(ws + off0 + 256);

    // zero acc[4] (+pad to 64 words) + num_pos[32*32] = 1088 words
    mbl_zero_kernel<<<1, 256, 0, stream>>>((unsigned*)(ws + off0), 1088);

    mbl_main_kernel<<<GRID_MAIN, TPB, 0, stream>>>(
        loc_t, loc_data, conf_t, conf, loss_c, acc, num_pos);

    mbl_select_kernel<<<BB, 1024, 0, stream>>>(loss_c, num_pos, acc);

    mbl_final_kernel<<<1, 64, 0, stream>>>(acc, num_pos, out);
}